// Round 3
// baseline (526.769 us; speedup 1.0000x reference)
//
#include <hip/hip_runtime.h>

#define IH 256
#define IW 256
#define ICX 128
#define ICY 128
#define NRINGS 16
#define RINGW 8

// One block per (batch, ring). 256 threads scan the ring's bounding box
// (clamped to the image), histogram the quantized integer pixel values
// (exact: values are floor((x*0.5+0.5)*255) in [0,255]) and accumulate
// exact integer sum / sum-of-squares per channel. Median via 256-bin cumsum.
__global__ __launch_bounds__(256)
void radial_ring_feats(const float* __restrict__ img, float* __restrict__ out) {
    const int b    = blockIdx.x;   // 0..255
    const int ring = blockIdx.y;   // 0..15
    const int tid  = threadIdx.x;

    const int Rout  = RINGW * (ring + 1);
    const int Rin   = RINGW * ring;
    const int R2out = Rout * Rout;
    const int R2in  = Rin * Rin;           // ring 0: d2 > 0 excludes exact center
    const int side  = 2 * Rout + 1;
    const int total = side * side;

    __shared__ unsigned int hist[3][256];
    __shared__ unsigned int s_sum[3];
    __shared__ unsigned int s_sq[3];
    __shared__ unsigned int s_cnt;

    // zero LDS
    #pragma unroll
    for (int i = 0; i < 3; ++i) hist[i][tid] = 0u;
    if (tid < 3) { s_sum[tid] = 0u; s_sq[tid] = 0u; }
    if (tid == 0) s_cnt = 0u;
    __syncthreads();

    unsigned int lsum0 = 0, lsum1 = 0, lsum2 = 0;
    unsigned int lsq0  = 0, lsq1  = 0, lsq2  = 0;
    unsigned int lcnt  = 0;

    const float* base = img + (size_t)b * 3 * IH * IW;

    for (int idx = tid; idx < total; idx += 256) {
        const int dy = idx / side - Rout;
        const int dx = idx % side - Rout;
        const int y  = ICY + dy;
        const int x  = ICX + dx;
        const int d2 = dx * dx + dy * dy;
        if ((unsigned)y < IH && (unsigned)x < IW && d2 <= R2out && d2 > R2in) {
            const int off = y * IW + x;
            // channel 0
            {
                float f = base[off];
                int iv = (int)floorf((f * 0.5f + 0.5f) * 255.0f);
                iv = min(max(iv, 0), 255);
                atomicAdd(&hist[0][iv], 1u);
                lsum0 += (unsigned)iv; lsq0 += (unsigned)(iv * iv);
            }
            // channel 1
            {
                float f = base[IH * IW + off];
                int iv = (int)floorf((f * 0.5f + 0.5f) * 255.0f);
                iv = min(max(iv, 0), 255);
                atomicAdd(&hist[1][iv], 1u);
                lsum1 += (unsigned)iv; lsq1 += (unsigned)(iv * iv);
            }
            // channel 2
            {
                float f = base[2 * IH * IW + off];
                int iv = (int)floorf((f * 0.5f + 0.5f) * 255.0f);
                iv = min(max(iv, 0), 255);
                atomicAdd(&hist[2][iv], 1u);
                lsum2 += (unsigned)iv; lsq2 += (unsigned)(iv * iv);
            }
            lcnt++;
        }
    }

    // wave (64-lane) shuffle reduction, then one atomic per wave per value
    #pragma unroll
    for (int o = 32; o > 0; o >>= 1) {
        lsum0 += (unsigned)__shfl_down((int)lsum0, o, 64);
        lsum1 += (unsigned)__shfl_down((int)lsum1, o, 64);
        lsum2 += (unsigned)__shfl_down((int)lsum2, o, 64);
        lsq0  += (unsigned)__shfl_down((int)lsq0,  o, 64);
        lsq1  += (unsigned)__shfl_down((int)lsq1,  o, 64);
        lsq2  += (unsigned)__shfl_down((int)lsq2,  o, 64);
        lcnt  += (unsigned)__shfl_down((int)lcnt,  o, 64);
    }
    if ((tid & 63) == 0) {
        atomicAdd(&s_sum[0], lsum0);
        atomicAdd(&s_sum[1], lsum1);
        atomicAdd(&s_sum[2], lsum2);
        atomicAdd(&s_sq[0], lsq0);
        atomicAdd(&s_sq[1], lsq1);
        atomicAdd(&s_sq[2], lsq2);
        atomicAdd(&s_cnt, lcnt);
    }
    __syncthreads();

    // threads 0..2: one channel each — mean/std (double, exact sums) + median
    if (tid < 3) {
        const int c = tid;
        const unsigned int n = s_cnt;
        const double dn   = (double)n;
        const double mean = (double)s_sum[c] / dn;
        double var = (double)s_sq[c] / dn - mean * mean;
        if (var < 0.0) var = 0.0;

        // order statistics: j1 = (n-1)/2, j2 = n/2 (equal when n odd)
        const unsigned int j1 = (n - 1u) >> 1;
        const unsigned int j2 = n >> 1;
        unsigned int cum = 0;
        int v1 = -1, v2 = -1;
        #pragma unroll 4
        for (int v = 0; v < 256; ++v) {
            cum += hist[c][v];
            if (v1 < 0 && cum > j1) v1 = v;
            if (cum > j2) { v2 = v; break; }
        }
        const float med = 0.5f * (float)(v1 + v2);

        float* o = out + ((size_t)b * NRINGS + ring) * 9;
        o[c]     = (float)mean;
        o[3 + c] = (float)sqrt(var);
        o[6 + c] = med;
    }
}

extern "C" void kernel_launch(void* const* d_in, const int* in_sizes, int n_in,
                              void* d_out, int out_size, void* d_ws, size_t ws_size,
                              hipStream_t stream) {
    const float* img = (const float*)d_in[0];
    float* out = (float*)d_out;
    dim3 grid(256, NRINGS);
    radial_ring_feats<<<grid, 256, 0, stream>>>(img, out);
}

// Round 6
// 312.120 us; speedup vs baseline: 1.6877x; 1.6877x over previous
//
#include <hip/hip_runtime.h>

#define IH 256
#define IW 256
#define NRINGS 16
// Global hist in d_ws: u32 words, layout [b][ring][c][128]; each word packs two
// u16 counts (bins 2w, 2w+1). Per-(b,ring,c) count <= 6233 so u16 never overflows.
#define HW_BRC 128
#define HW_B   (NRINGS * 3 * HW_BRC)          // 6144 words per batch
#define HW_TOT (256 * HW_B)                   // 1,572,864 words = 6.29 MB
#define HW_BYTES ((size_t)HW_TOT * 4)

// ---------- K0: zero the global hist ----------
__global__ __launch_bounds__(256)
void k0_zero(uint4* __restrict__ h) {
    h[blockIdx.x * 256 + threadIdx.x] = make_uint4(0u, 0u, 0u, 0u);  // grid sized exactly
}

// ---------- K1: scan image once, LDS hist per block, merge to global ----------
// grid (256 batches, 8 row-segments), 256 threads. Thread t owns float4-column
// (t&63) and rows ry = (t>>6) + 4k within its 32-row segment.
__global__ __launch_bounds__(256)
void k1_hist(const float* __restrict__ img, unsigned int* __restrict__ gh) {
    const int b   = blockIdx.x;
    const int s   = blockIdx.y;
    const int tid = threadIdx.x;

    __shared__ unsigned int hist[NRINGS * 3 * HW_BRC];   // 6144 words = 24 KiB

    for (int i = tid; i < NRINGS * 3 * HW_BRC; i += 256) hist[i] = 0u;
    __syncthreads();

    const int xg  = (tid & 63) * 4;       // first x of this thread's float4 group
    const int ry0 = tid >> 6;
    const float* base = img + (size_t)b * 3 * IH * IW;

    const int dx0 = xg - 128;
    int dxs[4];
    #pragma unroll
    for (int j = 0; j < 4; ++j) dxs[j] = (dx0 + j) * (dx0 + j);
    int admin = (dx0 <= 0 && dx0 + 3 >= 0) ? 0 : min(abs(dx0), abs(dx0 + 3));
    const int admin2 = admin * admin;

    for (int ry = ry0; ry < 32; ry += 4) {
        const int y   = (s << 5) + ry;
        const int dy  = y - 128;
        const int dy2 = dy * dy;
        if (dy2 + admin2 > 16384) continue;          // whole group outside circle

        const int off = y * IW + xg;
        const float4 f0 = *(const float4*)(base + off);
        const float4 f1 = *(const float4*)(base + IH * IW + off);
        const float4 f2 = *(const float4*)(base + 2 * IH * IW + off);
        const float va[3][4] = {{f0.x, f0.y, f0.z, f0.w},
                                {f1.x, f1.y, f1.z, f1.w},
                                {f2.x, f2.y, f2.z, f2.w}};

        #pragma unroll
        for (int j = 0; j < 4; ++j) {
            const int d2 = dy2 + dxs[j];
            if (d2 == 0 || d2 > 16384) continue;     // center excluded; outside circle
            // ring = ceil(sqrt(d2)/8) - 1, exact (float sqrt + integer correction)
            int k = (int)ceilf(sqrtf((float)d2) * 0.125f);
            if (64 * k * k < d2) k++;
            else if (k > 1 && 64 * (k - 1) * (k - 1) >= d2) k--;
            const int ring = k - 1;                  // 0..15
            #pragma unroll
            for (int c = 0; c < 3; ++c) {
                const float f = va[c][j];
                int iv = (int)floorf((f * 0.5f + 0.5f) * 255.0f);
                iv = min(max(iv, 0), 255);
                atomicAdd(&hist[(ring * 3 + c) * HW_BRC + (iv >> 1)],
                          1u << ((iv & 1) << 4));
            }
        }
    }

    __syncthreads();
    // coalesced merge, skip zero words (most rings untouched by a 32-row segment)
    unsigned int* gb = gh + (size_t)b * HW_B;
    for (int i = tid; i < HW_B; i += 256) {
        const unsigned int v = hist[i];
        if (v) atomicAdd(&gb[i], v);
    }
}

// ---------- K2: stats from global hist ----------
// grid (256, 16), 64 threads; lanes 0..2 handle one channel each.
__global__ __launch_bounds__(64)
void k2_stats(const unsigned int* __restrict__ gh, float* __restrict__ out) {
    const int b    = blockIdx.x;
    const int ring = blockIdx.y;
    const int c    = threadIdx.x;
    if (c >= 3) return;

    const unsigned int* h = gh + (size_t)b * HW_B + (ring * 3 + c) * HW_BRC;

    unsigned int n = 0, sum = 0, sumsq = 0;
    #pragma unroll 8
    for (int w = 0; w < HW_BRC; ++w) {
        const unsigned int v  = h[w];
        const unsigned int c0 = v & 0xffffu;
        const unsigned int c1 = v >> 16;
        const unsigned int v0 = 2 * w, v1 = 2 * w + 1;
        n     += c0 + c1;
        sum   += c0 * v0 + c1 * v1;
        sumsq += c0 * v0 * v0 + c1 * v1 * v1;
    }

    const double dn   = (double)n;
    const double mean = (double)sum / dn;
    double var = (double)sumsq / dn - mean * mean;
    if (var < 0.0) var = 0.0;

    const unsigned int j1 = (n - 1u) >> 1;
    const unsigned int j2 = n >> 1;
    unsigned int cum = 0;
    int v1i = -1, v2i = -1;
    for (int w = 0; w < HW_BRC; ++w) {
        const unsigned int v = h[w];
        cum += v & 0xffffu;
        if (v1i < 0 && cum > j1) v1i = 2 * w;
        if (v2i < 0 && cum > j2) { v2i = 2 * w; break; }
        cum += v >> 16;
        if (v1i < 0 && cum > j1) v1i = 2 * w + 1;
        if (v2i < 0 && cum > j2) { v2i = 2 * w + 1; break; }
    }

    float* o = out + ((size_t)b * NRINGS + ring) * 9;
    o[c]     = (float)mean;
    o[3 + c] = (float)sqrt(var);
    o[6 + c] = 0.5f * (float)(v1i + v2i);
}

// ---------- fallback (round-3 kernel, known-correct) if ws too small ----------
__global__ __launch_bounds__(256)
void radial_ring_feats(const float* __restrict__ img, float* __restrict__ out) {
    const int b = blockIdx.x, ring = blockIdx.y, tid = threadIdx.x;
    const int Rout = 8 * (ring + 1), Rin = 8 * ring;
    const int R2out = Rout * Rout, R2in = Rin * Rin;
    const int side = 2 * Rout + 1, total = side * side;
    __shared__ unsigned int hist[3][256];
    __shared__ unsigned int s_sum[3], s_sq[3], s_cnt;
    #pragma unroll
    for (int i = 0; i < 3; ++i) hist[i][tid] = 0u;
    if (tid < 3) { s_sum[tid] = 0u; s_sq[tid] = 0u; }
    if (tid == 0) s_cnt = 0u;
    __syncthreads();
    unsigned int ls[3] = {0,0,0}, lq[3] = {0,0,0}, lcnt = 0;
    const float* base = img + (size_t)b * 3 * IH * IW;
    for (int idx = tid; idx < total; idx += 256) {
        const int dy = idx / side - Rout, dx = idx % side - Rout;
        const int y = 128 + dy, x = 128 + dx, d2 = dx * dx + dy * dy;
        if ((unsigned)y < IH && (unsigned)x < IW && d2 <= R2out && d2 > R2in) {
            const int off = y * IW + x;
            #pragma unroll
            for (int c = 0; c < 3; ++c) {
                float f = base[c * IH * IW + off];
                int iv = (int)floorf((f * 0.5f + 0.5f) * 255.0f);
                iv = min(max(iv, 0), 255);
                atomicAdd(&hist[c][iv], 1u);
                ls[c] += (unsigned)iv; lq[c] += (unsigned)(iv * iv);
            }
            lcnt++;
        }
    }
    #pragma unroll
    for (int o = 32; o > 0; o >>= 1) {
        #pragma unroll
        for (int c = 0; c < 3; ++c) {
            ls[c] += (unsigned)__shfl_down((int)ls[c], o, 64);
            lq[c] += (unsigned)__shfl_down((int)lq[c], o, 64);
        }
        lcnt += (unsigned)__shfl_down((int)lcnt, o, 64);
    }
    if ((tid & 63) == 0) {
        #pragma unroll
        for (int c = 0; c < 3; ++c) { atomicAdd(&s_sum[c], ls[c]); atomicAdd(&s_sq[c], lq[c]); }
        atomicAdd(&s_cnt, lcnt);
    }
    __syncthreads();
    if (tid < 3) {
        const int c = tid;
        const unsigned int n = s_cnt;
        const double mean = (double)s_sum[c] / (double)n;
        double var = (double)s_sq[c] / (double)n - mean * mean;
        if (var < 0.0) var = 0.0;
        const unsigned int j1 = (n - 1u) >> 1, j2 = n >> 1;
        unsigned int cum = 0; int v1 = -1, v2 = -1;
        for (int v = 0; v < 256; ++v) {
            cum += hist[c][v];
            if (v1 < 0 && cum > j1) v1 = v;
            if (cum > j2) { v2 = v; break; }
        }
        float* o = out + ((size_t)b * NRINGS + ring) * 9;
        o[c] = (float)mean; o[3 + c] = (float)sqrt(var); o[6 + c] = 0.5f * (float)(v1 + v2);
    }
}

extern "C" void kernel_launch(void* const* d_in, const int* in_sizes, int n_in,
                              void* d_out, int out_size, void* d_ws, size_t ws_size,
                              hipStream_t stream) {
    const float* img = (const float*)d_in[0];
    float* out = (float*)d_out;
    if (ws_size >= HW_BYTES) {
        unsigned int* gh = (unsigned int*)d_ws;
        k0_zero<<<HW_TOT / 4 / 256, 256, 0, stream>>>((uint4*)gh);   // 1536 blocks exact
        k1_hist<<<dim3(256, 8), 256, 0, stream>>>(img, gh);
        k2_stats<<<dim3(256, NRINGS), 64, 0, stream>>>(gh, out);
    } else {
        radial_ring_feats<<<dim3(256, NRINGS), 256, 0, stream>>>(img, out);
    }
}

// Round 8
// 284.864 us; speedup vs baseline: 1.8492x; 1.0957x over previous
//
#include <hip/hip_runtime.h>

#define IH 256
#define IW 256
#define NRINGS 16
#define HW_BRC 128   // 128 u32 words per (ring,c): two u16 counts per word

// One block per batch image. 1024 threads (16 waves); wave w's 64 lanes cover
// one full 256-px row (4 px each, float4), rows w, w+16, ..., w+240.
// Full [16][3][128] packed-u16 histogram lives in 24 KiB LDS; the same kernel
// derives mean/std (exact integer sums -> double) and median (cumsum) for all
// 48 (ring,channel) pairs. No workspace, no global atomics, single launch.
__global__ __launch_bounds__(1024)
void radial_fused(const float* __restrict__ img, float* __restrict__ out) {
    const int b   = blockIdx.x;
    const int tid = threadIdx.x;

    __shared__ unsigned int hist[NRINGS * 3 * HW_BRC];   // 6144 words = 24 KiB

    for (int i = tid; i < NRINGS * 3 * HW_BRC; i += 1024) hist[i] = 0u;
    __syncthreads();

    const int xg = (tid & 63) * 4;     // first x of this thread's float4 group
    const int r0 = tid >> 6;           // 0..15 (== wave id)
    const float* base = img + (size_t)b * 3 * IH * IW;

    const int dx0 = xg - 128;
    int dxs[4];
    #pragma unroll
    for (int j = 0; j < 4; ++j) dxs[j] = (dx0 + j) * (dx0 + j);
    const int admin  = (dx0 <= 0 && dx0 + 3 >= 0) ? 0 : min(abs(dx0), abs(dx0 + 3));
    const int admin2 = admin * admin;

    for (int k = 0; k < 16; ++k) {
        const int y   = r0 + (k << 4);
        const int dy  = y - 128;
        const int dy2 = dy * dy;
        if (dy2 + admin2 > 16384) continue;          // whole float4 group outside circle

        const int off = y * IW + xg;
        const float4 f0 = *(const float4*)(base + off);
        const float4 f1 = *(const float4*)(base + IH * IW + off);
        const float4 f2 = *(const float4*)(base + 2 * IH * IW + off);
        const float va[3][4] = {{f0.x, f0.y, f0.z, f0.w},
                                {f1.x, f1.y, f1.z, f1.w},
                                {f2.x, f2.y, f2.z, f2.w}};

        #pragma unroll
        for (int j = 0; j < 4; ++j) {
            const int d2 = dy2 + dxs[j];
            if (d2 == 0 || d2 > 16384) continue;     // center excluded; outside circle
            // ring = ceil(sqrt(d2)/8) - 1, exact (float sqrt + integer correction)
            int kk = (int)ceilf(sqrtf((float)d2) * 0.125f);
            if (64 * kk * kk < d2) kk++;
            else if (kk > 1 && 64 * (kk - 1) * (kk - 1) >= d2) kk--;
            const int ring = kk - 1;                 // 0..15
            #pragma unroll
            for (int c = 0; c < 3; ++c) {
                const float f = va[c][j];
                int iv = (int)floorf((f * 0.5f + 0.5f) * 255.0f);
                iv = min(max(iv, 0), 255);
                atomicAdd(&hist[(ring * 3 + c) * HW_BRC + (iv >> 1)],
                          1u << ((iv & 1) << 4));
            }
        }
    }

    __syncthreads();

    // stats: one thread per (ring, channel) pair
    if (tid < NRINGS * 3) {
        const int ring = tid / 3;
        const int c    = tid - ring * 3;
        const unsigned int* h = &hist[(ring * 3 + c) * HW_BRC];

        unsigned int n = 0, sum = 0, sumsq = 0;
        #pragma unroll 8
        for (int w = 0; w < HW_BRC; ++w) {
            const unsigned int v  = h[w];
            const unsigned int c0 = v & 0xffffu;
            const unsigned int c1 = v >> 16;
            const unsigned int v0 = 2 * w, v1 = 2 * w + 1;
            n     += c0 + c1;
            sum   += c0 * v0 + c1 * v1;
            sumsq += c0 * v0 * v0 + c1 * v1 * v1;
        }

        const double dn   = (double)n;
        const double mean = (double)sum / dn;
        double var = (double)sumsq / dn - mean * mean;
        if (var < 0.0) var = 0.0;

        const unsigned int j1 = (n - 1u) >> 1;
        const unsigned int j2 = n >> 1;
        unsigned int cum = 0;
        int v1i = -1, v2i = -1;
        for (int w = 0; w < HW_BRC; ++w) {
            const unsigned int v = h[w];
            cum += v & 0xffffu;
            if (v1i < 0 && cum > j1) v1i = 2 * w;
            if (v2i < 0 && cum > j2) { v2i = 2 * w; break; }
            cum += v >> 16;
            if (v1i < 0 && cum > j1) v1i = 2 * w + 1;
            if (v2i < 0 && cum > j2) { v2i = 2 * w + 1; break; }
        }

        float* o = out + ((size_t)b * NRINGS + ring) * 9;
        o[c]     = (float)mean;
        o[3 + c] = (float)sqrt(var);
        o[6 + c] = 0.5f * (float)(v1i + v2i);
    }
}

extern "C" void kernel_launch(void* const* d_in, const int* in_sizes, int n_in,
                              void* d_out, int out_size, void* d_ws, size_t ws_size,
                              hipStream_t stream) {
    const float* img = (const float*)d_in[0];
    float* out = (float*)d_out;
    radial_fused<<<256, 1024, 0, stream>>>(img, out);
}